// Round 2
// baseline (76.180 us; speedup 1.0000x reference)
//
#include <hip/hip_runtime.h>

// Clustering layer: q[n,k] = t-dist kernel of ||z_n - c_k||^2, row-normalized.
// N=131072, K=100 (pad->112), D=256. f32 in/out; f16 MFMA for the dot products.
//
// R1: 32 rows/wave (acc[2][7]), __launch_bounds__(256,4) -> 4 waves/SIMD,
//     depth-1 A-prefetch, nontemporal z loads + q stores.
// Memory-bound: ~187 MB HBM -> ~30us floor.

typedef __attribute__((ext_vector_type(8))) _Float16 f16x8;
typedef __attribute__((ext_vector_type(4))) _Float16 f16x4;
typedef __attribute__((ext_vector_type(4))) float    f32x4;

#define DDIM 256
#define KCL  100
#define KPAD 112   // 7 * 16
#define NT   7     // column tiles of 16

// ---------------- kernel 1: clusters f32 -> f16 (padded) + ||c||^2 ----------
__global__ __launch_bounds__(64) void prep_clusters(const float* __restrict__ c,
                                                    _Float16* __restrict__ cb,
                                                    float* __restrict__ c2) {
    const int r    = blockIdx.x;    // 0..111
    const int lane = threadIdx.x;   // 0..63, each lane handles 4 elems
    f32x4 v = {0.f, 0.f, 0.f, 0.f};
    if (r < KCL) {
        v = reinterpret_cast<const f32x4*>(c)[r * (DDIM / 4) + lane];
    }
    f16x4 b;
    b[0] = (_Float16)v[0]; b[1] = (_Float16)v[1];
    b[2] = (_Float16)v[2]; b[3] = (_Float16)v[3];
    reinterpret_cast<f16x4*>(cb)[r * (DDIM / 4) + lane] = b;

    float ss = v[0]*v[0] + v[1]*v[1] + v[2]*v[2] + v[3]*v[3];
    #pragma unroll
    for (int m = 1; m < 64; m <<= 1) ss += __shfl_xor(ss, m);
    if (lane == 0) c2[r] = ss;
}

// ---------------- kernel 2: main fused GEMM + epilogue -----------------------
// Block = 256 threads = 4 waves. Each wave: 32 rows x 112 cols (2x7 MFMA tiles).
// Grid = N/128 blocks.
__global__ __launch_bounds__(256, 4) void cluster_q(const float* __restrict__ z,
                                                    const _Float16* __restrict__ cb,
                                                    const float* __restrict__ c2,
                                                    float* __restrict__ out) {
    const int lane = threadIdx.x & 63;
    const int wv   = threadIdx.x >> 6;     // 0..3
    const int g    = lane >> 4;            // k-group 0..3
    const int c16  = lane & 15;            // row (A) / col (B) within tile
    const long rowbase = (long)blockIdx.x * 128 + wv * 32;

    f32x4 acc[2][NT];
    #pragma unroll
    for (int i = 0; i < 2; ++i)
        #pragma unroll
        for (int t = 0; t < NT; ++t)
            acc[i][t] = f32x4{0.f, 0.f, 0.f, 0.f};

    float zsq[2] = {0.f, 0.f};

    // per-lane base pointers (A rows c16 and 16+c16, k-offset 8*g)
    const float* p0 = z + (rowbase + c16) * DDIM + 8 * g;
    const float* p1 = p0 + 16 * DDIM;
    const _Float16* bb = cb + c16 * DDIM + 8 * g;

    // prefetch step 0
    f32x4 lo0 = __builtin_nontemporal_load(reinterpret_cast<const f32x4*>(p0));
    f32x4 hi0 = __builtin_nontemporal_load(reinterpret_cast<const f32x4*>(p0 + 4));
    f32x4 lo1 = __builtin_nontemporal_load(reinterpret_cast<const f32x4*>(p1));
    f32x4 hi1 = __builtin_nontemporal_load(reinterpret_cast<const f32x4*>(p1 + 4));

    // K loop: 8 steps of 32. A from global f32 (convert), B from f16 workspace.
    // A and B use identical (group,reg)->k indexing -> HW k-slot convention
    // cancels; only the C/D layout (epilogue) is load-bearing.
    #pragma unroll 1
    for (int s = 0; s < 8; ++s) {
        const int kn = (s < 7) ? 32 * (s + 1) : 0;   // next-step prefetch offset
        f32x4 nlo0 = __builtin_nontemporal_load(reinterpret_cast<const f32x4*>(p0 + kn));
        f32x4 nhi0 = __builtin_nontemporal_load(reinterpret_cast<const f32x4*>(p0 + kn + 4));
        f32x4 nlo1 = __builtin_nontemporal_load(reinterpret_cast<const f32x4*>(p1 + kn));
        f32x4 nhi1 = __builtin_nontemporal_load(reinterpret_cast<const f32x4*>(p1 + kn + 4));

        zsq[0] += lo0[0]*lo0[0] + lo0[1]*lo0[1] + lo0[2]*lo0[2] + lo0[3]*lo0[3]
                + hi0[0]*hi0[0] + hi0[1]*hi0[1] + hi0[2]*hi0[2] + hi0[3]*hi0[3];
        zsq[1] += lo1[0]*lo1[0] + lo1[1]*lo1[1] + lo1[2]*lo1[2] + lo1[3]*lo1[3]
                + hi1[0]*hi1[0] + hi1[1]*hi1[1] + hi1[2]*hi1[2] + hi1[3]*hi1[3];

        f16x8 a0, a1;
        a0[0] = (_Float16)lo0[0]; a0[1] = (_Float16)lo0[1];
        a0[2] = (_Float16)lo0[2]; a0[3] = (_Float16)lo0[3];
        a0[4] = (_Float16)hi0[0]; a0[5] = (_Float16)hi0[1];
        a0[6] = (_Float16)hi0[2]; a0[7] = (_Float16)hi0[3];
        a1[0] = (_Float16)lo1[0]; a1[1] = (_Float16)lo1[1];
        a1[2] = (_Float16)lo1[2]; a1[3] = (_Float16)lo1[3];
        a1[4] = (_Float16)hi1[0]; a1[5] = (_Float16)hi1[1];
        a1[6] = (_Float16)hi1[2]; a1[7] = (_Float16)hi1[3];

        const _Float16* bs = bb + 32 * s;
        #pragma unroll
        for (int t = 0; t < NT; ++t) {
            f16x8 b = *reinterpret_cast<const f16x8*>(bs + t * 16 * DDIM);
            acc[0][t] = __builtin_amdgcn_mfma_f32_16x16x32_f16(a0, b, acc[0][t], 0, 0, 0);
            acc[1][t] = __builtin_amdgcn_mfma_f32_16x16x32_f16(a1, b, acc[1][t], 0, 0, 0);
        }

        lo0 = nlo0; hi0 = nhi0; lo1 = nlo1; hi1 = nhi1;
    }

    // ||z_row||^2: lane covered 64 of row (i*16 + c16)'s 256 k-elems;
    // sum the 4 k-groups (lanes differing in bits 4..5).
    #pragma unroll
    for (int i = 0; i < 2; ++i) {
        zsq[i] += __shfl_xor(zsq[i], 16);
        zsq[i] += __shfl_xor(zsq[i], 32);
    }
    // now lane l holds z2 of row (l & 15) (plus i*16)

    float c2v[NT];
    #pragma unroll
    for (int t = 0; t < NT; ++t) c2v[t] = c2[t * 16 + c16];

    // Epilogue. C/D layout (verified, guide §3): col = lane&15, row = g*4 + reg.
    #pragma unroll
    for (int i = 0; i < 2; ++i) {
        #pragma unroll
        for (int j = 0; j < 4; ++j) {
            const int r = 4 * g + j;                 // row within 16-tile
            const float z2 = __shfl(zsq[i], r);      // lane r holds row r's norm
            float qv[NT];
            float rs = 0.f;
            #pragma unroll
            for (int t = 0; t < NT; ++t) {
                const float dot = acc[i][t][j];
                const float d2 = fmaxf(z2 + c2v[t] - 2.f * dot, 0.f);
                const float q = __builtin_amdgcn_rcpf(1.f + d2);
                qv[t] = q;
                if (t < 6 || c16 < 4) rs += q;       // mask padded cols 100..111
            }
            // row sum across the 16 lanes of this group (cols)
            rs += __shfl_xor(rs, 1);
            rs += __shfl_xor(rs, 2);
            rs += __shfl_xor(rs, 4);
            rs += __shfl_xor(rs, 8);
            const float rinv = __builtin_amdgcn_rcpf(rs);

            float* orow = out + (rowbase + i * 16 + r) * KCL;
            #pragma unroll
            for (int t = 0; t < NT; ++t) {
                const int col = t * 16 + c16;
                if (col < KCL)
                    __builtin_nontemporal_store(qv[t] * rinv, orow + col);
            }
        }
    }
}

// ---------------- launcher ---------------------------------------------------
extern "C" void kernel_launch(void* const* d_in, const int* in_sizes, int n_in,
                              void* d_out, int out_size, void* d_ws, size_t ws_size,
                              hipStream_t stream) {
    const float* z  = (const float*)d_in[0];
    const float* cl = (const float*)d_in[1];
    float* out = (float*)d_out;

    _Float16* cb = (_Float16*)d_ws;                                  // 112*256*2 B
    float*    c2 = (float*)((char*)d_ws + KPAD * DDIM * sizeof(_Float16));

    const int N = in_sizes[0] / DDIM;   // 131072

    prep_clusters<<<KPAD, 64, 0, stream>>>(cl, cb, c2);
    cluster_q<<<N / 128, 256, 0, stream>>>(z, cb, c2, out);
}

// Round 3
// 58.526 us; speedup vs baseline: 1.3016x; 1.3016x over previous
//
#include <hip/hip_runtime.h>

// Clustering layer: q[n,k] = t-dist kernel of ||z_n - c_k||^2, row-normalized.
// N=131072, K=100 (pad->112), D=256. f32 in/out; f16 MFMA for the dot products.
//
// R2: R1 structure (32 rows/wave, launch_bounds(256,4), depth-1 A-prefetch)
//     with ALL nontemporal qualifiers removed (R1 post-mortem: nt broke
//     sibling-load line reuse + L3 residency across graph replays; 49->76us).

typedef __attribute__((ext_vector_type(8))) _Float16 f16x8;
typedef __attribute__((ext_vector_type(4))) _Float16 f16x4;
typedef __attribute__((ext_vector_type(4))) float    f32x4;

#define DDIM 256
#define KCL  100
#define KPAD 112   // 7 * 16
#define NT   7     // column tiles of 16

// ---------------- kernel 1: clusters f32 -> f16 (padded) + ||c||^2 ----------
__global__ __launch_bounds__(64) void prep_clusters(const float* __restrict__ c,
                                                    _Float16* __restrict__ cb,
                                                    float* __restrict__ c2) {
    const int r    = blockIdx.x;    // 0..111
    const int lane = threadIdx.x;   // 0..63, each lane handles 4 elems
    f32x4 v = {0.f, 0.f, 0.f, 0.f};
    if (r < KCL) {
        v = reinterpret_cast<const f32x4*>(c)[r * (DDIM / 4) + lane];
    }
    f16x4 b;
    b[0] = (_Float16)v[0]; b[1] = (_Float16)v[1];
    b[2] = (_Float16)v[2]; b[3] = (_Float16)v[3];
    reinterpret_cast<f16x4*>(cb)[r * (DDIM / 4) + lane] = b;

    float ss = v[0]*v[0] + v[1]*v[1] + v[2]*v[2] + v[3]*v[3];
    #pragma unroll
    for (int m = 1; m < 64; m <<= 1) ss += __shfl_xor(ss, m);
    if (lane == 0) c2[r] = ss;
}

// ---------------- kernel 2: main fused GEMM + epilogue -----------------------
// Block = 256 threads = 4 waves. Each wave: 32 rows x 112 cols (2x7 MFMA tiles).
// Grid = N/128 blocks.
__global__ __launch_bounds__(256, 4) void cluster_q(const float* __restrict__ z,
                                                    const _Float16* __restrict__ cb,
                                                    const float* __restrict__ c2,
                                                    float* __restrict__ out) {
    const int lane = threadIdx.x & 63;
    const int wv   = threadIdx.x >> 6;     // 0..3
    const int g    = lane >> 4;            // k-group 0..3
    const int c16  = lane & 15;            // row (A) / col (B) within tile
    const long rowbase = (long)blockIdx.x * 128 + wv * 32;

    f32x4 acc[2][NT];
    #pragma unroll
    for (int i = 0; i < 2; ++i)
        #pragma unroll
        for (int t = 0; t < NT; ++t)
            acc[i][t] = f32x4{0.f, 0.f, 0.f, 0.f};

    float zsq[2] = {0.f, 0.f};

    // per-lane base pointers (A rows c16 and 16+c16, k-offset 8*g)
    const float* p0 = z + (rowbase + c16) * DDIM + 8 * g;
    const float* p1 = p0 + 16 * DDIM;
    const _Float16* bb = cb + c16 * DDIM + 8 * g;

    // prefetch step 0
    f32x4 lo0 = *reinterpret_cast<const f32x4*>(p0);
    f32x4 hi0 = *reinterpret_cast<const f32x4*>(p0 + 4);
    f32x4 lo1 = *reinterpret_cast<const f32x4*>(p1);
    f32x4 hi1 = *reinterpret_cast<const f32x4*>(p1 + 4);

    // K loop: 8 steps of 32. A from global f32 (convert), B from f16 workspace.
    // A and B use identical (group,reg)->k indexing -> HW k-slot convention
    // cancels; only the C/D layout (epilogue) is load-bearing.
    #pragma unroll 1
    for (int s = 0; s < 8; ++s) {
        const int kn = (s < 7) ? 32 * (s + 1) : 0;   // next-step prefetch offset
        f32x4 nlo0 = *reinterpret_cast<const f32x4*>(p0 + kn);
        f32x4 nhi0 = *reinterpret_cast<const f32x4*>(p0 + kn + 4);
        f32x4 nlo1 = *reinterpret_cast<const f32x4*>(p1 + kn);
        f32x4 nhi1 = *reinterpret_cast<const f32x4*>(p1 + kn + 4);

        zsq[0] += lo0[0]*lo0[0] + lo0[1]*lo0[1] + lo0[2]*lo0[2] + lo0[3]*lo0[3]
                + hi0[0]*hi0[0] + hi0[1]*hi0[1] + hi0[2]*hi0[2] + hi0[3]*hi0[3];
        zsq[1] += lo1[0]*lo1[0] + lo1[1]*lo1[1] + lo1[2]*lo1[2] + lo1[3]*lo1[3]
                + hi1[0]*hi1[0] + hi1[1]*hi1[1] + hi1[2]*hi1[2] + hi1[3]*hi1[3];

        f16x8 a0, a1;
        a0[0] = (_Float16)lo0[0]; a0[1] = (_Float16)lo0[1];
        a0[2] = (_Float16)lo0[2]; a0[3] = (_Float16)lo0[3];
        a0[4] = (_Float16)hi0[0]; a0[5] = (_Float16)hi0[1];
        a0[6] = (_Float16)hi0[2]; a0[7] = (_Float16)hi0[3];
        a1[0] = (_Float16)lo1[0]; a1[1] = (_Float16)lo1[1];
        a1[2] = (_Float16)lo1[2]; a1[3] = (_Float16)lo1[3];
        a1[4] = (_Float16)hi1[0]; a1[5] = (_Float16)hi1[1];
        a1[6] = (_Float16)hi1[2]; a1[7] = (_Float16)hi1[3];

        const _Float16* bs = bb + 32 * s;
        #pragma unroll
        for (int t = 0; t < NT; ++t) {
            f16x8 b = *reinterpret_cast<const f16x8*>(bs + t * 16 * DDIM);
            acc[0][t] = __builtin_amdgcn_mfma_f32_16x16x32_f16(a0, b, acc[0][t], 0, 0, 0);
            acc[1][t] = __builtin_amdgcn_mfma_f32_16x16x32_f16(a1, b, acc[1][t], 0, 0, 0);
        }

        lo0 = nlo0; hi0 = nhi0; lo1 = nlo1; hi1 = nhi1;
    }

    // ||z_row||^2: lane covered 64 of row (i*16 + c16)'s 256 k-elems;
    // sum the 4 k-groups (lanes differing in bits 4..5).
    #pragma unroll
    for (int i = 0; i < 2; ++i) {
        zsq[i] += __shfl_xor(zsq[i], 16);
        zsq[i] += __shfl_xor(zsq[i], 32);
    }
    // now lane l holds z2 of row (l & 15) (plus i*16)

    float c2v[NT];
    #pragma unroll
    for (int t = 0; t < NT; ++t) c2v[t] = c2[t * 16 + c16];

    // Epilogue. C/D layout (verified, guide §3): col = lane&15, row = g*4 + reg.
    #pragma unroll
    for (int i = 0; i < 2; ++i) {
        #pragma unroll
        for (int j = 0; j < 4; ++j) {
            const int r = 4 * g + j;                 // row within 16-tile
            const float z2 = __shfl(zsq[i], r);      // lane r holds row r's norm
            float qv[NT];
            float rs = 0.f;
            #pragma unroll
            for (int t = 0; t < NT; ++t) {
                const float dot = acc[i][t][j];
                const float d2 = fmaxf(z2 + c2v[t] - 2.f * dot, 0.f);
                const float q = __builtin_amdgcn_rcpf(1.f + d2);
                qv[t] = q;
                if (t < 6 || c16 < 4) rs += q;       // mask padded cols 100..111
            }
            // row sum across the 16 lanes of this group (cols)
            rs += __shfl_xor(rs, 1);
            rs += __shfl_xor(rs, 2);
            rs += __shfl_xor(rs, 4);
            rs += __shfl_xor(rs, 8);
            const float rinv = __builtin_amdgcn_rcpf(rs);

            float* orow = out + (rowbase + i * 16 + r) * KCL;
            #pragma unroll
            for (int t = 0; t < NT; ++t) {
                const int col = t * 16 + c16;
                if (col < KCL)
                    orow[col] = qv[t] * rinv;
            }
        }
    }
}

// ---------------- launcher ---------------------------------------------------
extern "C" void kernel_launch(void* const* d_in, const int* in_sizes, int n_in,
                              void* d_out, int out_size, void* d_ws, size_t ws_size,
                              hipStream_t stream) {
    const float* z  = (const float*)d_in[0];
    const float* cl = (const float*)d_in[1];
    float* out = (float*)d_out;

    _Float16* cb = (_Float16*)d_ws;                                  // 112*256*2 B
    float*    c2 = (float*)((char*)d_ws + KPAD * DDIM * sizeof(_Float16));

    const int N = in_sizes[0] / DDIM;   // 131072

    prep_clusters<<<KPAD, 64, 0, stream>>>(cl, cb, c2);
    cluster_q<<<N / 128, 256, 0, stream>>>(z, cb, c2, out);
}

// Round 4
// 41.719 us; speedup vs baseline: 1.8260x; 1.4029x over previous
//
#include <hip/hip_runtime.h>

// Clustering layer: q[n,k] = t-dist kernel of ||z_n - c_k||^2, row-normalized.
// N=131072, K=100 (pad->112), D=256. f32 in/out; f16 MFMA for the dot products.
//
// R3: back to 64 rows/wave (R0 tile, 28 MFMA/step), B panel staged in LDS
//     (56KB/block, XOR-swizzled byte^=(row&7)<<4 -> conflict-free ds_read_b128),
//     depth-1 A-prefetch kept. R2 post-mortem: latency-bound on unprefetched
//     per-step B vmem loads; all pipes <10% busy, z is L3-resident on replays.

typedef __attribute__((ext_vector_type(8))) _Float16 f16x8;
typedef __attribute__((ext_vector_type(4))) _Float16 f16x4;
typedef __attribute__((ext_vector_type(4))) float    f32x4;

#define DDIM 256
#define KCL  100
#define KPAD 112   // 7 * 16
#define NT   7     // column tiles of 16

// ---------------- kernel 1: clusters f32 -> f16 (padded) + ||c||^2 ----------
__global__ __launch_bounds__(64) void prep_clusters(const float* __restrict__ c,
                                                    _Float16* __restrict__ cb,
                                                    float* __restrict__ c2) {
    const int r    = blockIdx.x;    // 0..111
    const int lane = threadIdx.x;   // 0..63, each lane handles 4 elems
    f32x4 v = {0.f, 0.f, 0.f, 0.f};
    if (r < KCL) {
        v = reinterpret_cast<const f32x4*>(c)[r * (DDIM / 4) + lane];
    }
    f16x4 b;
    b[0] = (_Float16)v[0]; b[1] = (_Float16)v[1];
    b[2] = (_Float16)v[2]; b[3] = (_Float16)v[3];
    reinterpret_cast<f16x4*>(cb)[r * (DDIM / 4) + lane] = b;

    float ss = v[0]*v[0] + v[1]*v[1] + v[2]*v[2] + v[3]*v[3];
    #pragma unroll
    for (int m = 1; m < 64; m <<= 1) ss += __shfl_xor(ss, m);
    if (lane == 0) c2[r] = ss;
}

// ---------------- kernel 2: main fused GEMM + epilogue -----------------------
// Block = 256 threads = 4 waves. Each wave: 64 rows x 112 cols (4x7 MFMA tiles).
// Grid = N/256 blocks. B panel lives in swizzled LDS.
__global__ __launch_bounds__(256, 2) void cluster_q(const float* __restrict__ z,
                                                    const _Float16* __restrict__ cb,
                                                    const float* __restrict__ c2,
                                                    float* __restrict__ out) {
    __shared__ _Float16 Bs[KPAD * DDIM];   // 57,344 B

    const int tid  = threadIdx.x;
    const int lane = tid & 63;
    const int wv   = tid >> 6;             // 0..3
    const int g    = lane >> 4;            // k-group 0..3
    const int c16  = lane & 15;            // row (A) / col (B) within tile

    // ---- stage B panel into LDS, swizzled: byte ^= (row&7)<<4 ----
    // 112 rows x 512 B = 3584 chunks of 16 B; 256 threads x 14 iters.
    #pragma unroll
    for (int j = 0; j < 14; ++j) {
        const int idx  = j * 256 + tid;
        const int r    = idx >> 5;         // row 0..111
        const int cw   = idx & 31;         // 16B chunk within row
        f16x8 v = *reinterpret_cast<const f16x8*>(cb + r * DDIM + cw * 8);
        *reinterpret_cast<f16x8*>(reinterpret_cast<char*>(Bs)
            + r * 512 + ((cw * 16) ^ ((r & 7) << 4))) = v;
    }
    __syncthreads();

    const long rowbase = (long)blockIdx.x * 256 + wv * 64;

    f32x4 acc[4][NT];
    #pragma unroll
    for (int i = 0; i < 4; ++i)
        #pragma unroll
        for (int t = 0; t < NT; ++t)
            acc[i][t] = f32x4{0.f, 0.f, 0.f, 0.f};

    float zsq[4] = {0.f, 0.f, 0.f, 0.f};

    // per-lane A pointers: rows (i*16 + c16), k-offset 8*g
    const float* p[4];
    #pragma unroll
    for (int i = 0; i < 4; ++i)
        p[i] = z + (rowbase + i * 16 + c16) * DDIM + 8 * g;

    // per-lane swizzled B row bases
    const int rx = (c16 & 7) << 4;
    const char* bp[NT];
    #pragma unroll
    for (int t = 0; t < NT; ++t)
        bp[t] = reinterpret_cast<const char*>(Bs) + (t * 16 + c16) * 512;

    // prefetch step 0 A
    f32x4 lo[4], hi[4];
    #pragma unroll
    for (int i = 0; i < 4; ++i) {
        lo[i] = *reinterpret_cast<const f32x4*>(p[i]);
        hi[i] = *reinterpret_cast<const f32x4*>(p[i] + 4);
    }

    // K loop: 8 steps of 32. A from global (prefetched), B from swizzled LDS.
    // A and B use identical (group,reg)->k indexing -> HW k-slot convention
    // cancels; only the C/D layout (epilogue) is load-bearing.
    #pragma unroll 1
    for (int s = 0; s < 8; ++s) {
        const int kn = (s < 7) ? 32 * (s + 1) : 0;   // next-step prefetch
        f32x4 nlo[4], nhi[4];
        #pragma unroll
        for (int i = 0; i < 4; ++i) {
            nlo[i] = *reinterpret_cast<const f32x4*>(p[i] + kn);
            nhi[i] = *reinterpret_cast<const f32x4*>(p[i] + kn + 4);
        }

        f16x8 a[4];
        #pragma unroll
        for (int i = 0; i < 4; ++i) {
            zsq[i] += lo[i][0]*lo[i][0] + lo[i][1]*lo[i][1]
                    + lo[i][2]*lo[i][2] + lo[i][3]*lo[i][3]
                    + hi[i][0]*hi[i][0] + hi[i][1]*hi[i][1]
                    + hi[i][2]*hi[i][2] + hi[i][3]*hi[i][3];
            f16x8 av;
            av[0] = (_Float16)lo[i][0]; av[1] = (_Float16)lo[i][1];
            av[2] = (_Float16)lo[i][2]; av[3] = (_Float16)lo[i][3];
            av[4] = (_Float16)hi[i][0]; av[5] = (_Float16)hi[i][1];
            av[6] = (_Float16)hi[i][2]; av[7] = (_Float16)hi[i][3];
            a[i] = av;
        }

        const int sb = 64 * s + 16 * g;
        #pragma unroll
        for (int t = 0; t < NT; ++t) {
            f16x8 b = *reinterpret_cast<const f16x8*>(bp[t] + (sb ^ rx));
            #pragma unroll
            for (int i = 0; i < 4; ++i)
                acc[i][t] = __builtin_amdgcn_mfma_f32_16x16x32_f16(a[i], b, acc[i][t], 0, 0, 0);
        }

        #pragma unroll
        for (int i = 0; i < 4; ++i) { lo[i] = nlo[i]; hi[i] = nhi[i]; }
    }

    // ||z_row||^2: sum the 4 k-groups (lanes differing in bits 4..5)
    #pragma unroll
    for (int i = 0; i < 4; ++i) {
        zsq[i] += __shfl_xor(zsq[i], 16);
        zsq[i] += __shfl_xor(zsq[i], 32);
    }
    // now lane l holds z2 of row (l & 15) (plus i*16)

    float c2v[NT];
    #pragma unroll
    for (int t = 0; t < NT; ++t) c2v[t] = c2[t * 16 + c16];

    // Epilogue. C/D layout (verified, guide §3): col = lane&15, row = g*4 + reg.
    #pragma unroll
    for (int i = 0; i < 4; ++i) {
        #pragma unroll
        for (int j = 0; j < 4; ++j) {
            const int r = 4 * g + j;                 // row within 16-tile
            const float z2 = __shfl(zsq[i], r);      // lane r holds row r's norm
            float qv[NT];
            float rs = 0.f;
            #pragma unroll
            for (int t = 0; t < NT; ++t) {
                const float dot = acc[i][t][j];
                const float d2 = fmaxf(z2 + c2v[t] - 2.f * dot, 0.f);
                const float q = __builtin_amdgcn_rcpf(1.f + d2);
                qv[t] = q;
                if (t < 6 || c16 < 4) rs += q;       // mask padded cols 100..111
            }
            // row sum across the 16 lanes of this group (cols)
            rs += __shfl_xor(rs, 1);
            rs += __shfl_xor(rs, 2);
            rs += __shfl_xor(rs, 4);
            rs += __shfl_xor(rs, 8);
            const float rinv = __builtin_amdgcn_rcpf(rs);

            float* orow = out + (rowbase + i * 16 + r) * KCL;
            #pragma unroll
            for (int t = 0; t < NT; ++t) {
                const int col = t * 16 + c16;
                if (col < KCL)
                    orow[col] = qv[t] * rinv;
            }
        }
    }
}

// ---------------- launcher ---------------------------------------------------
extern "C" void kernel_launch(void* const* d_in, const int* in_sizes, int n_in,
                              void* d_out, int out_size, void* d_ws, size_t ws_size,
                              hipStream_t stream) {
    const float* z  = (const float*)d_in[0];
    const float* cl = (const float*)d_in[1];
    float* out = (float*)d_out;

    _Float16* cb = (_Float16*)d_ws;                                  // 112*256*2 B
    float*    c2 = (float*)((char*)d_ws + KPAD * DDIM * sizeof(_Float16));

    const int N = in_sizes[0] / DDIM;   // 131072

    prep_clusters<<<KPAD, 64, 0, stream>>>(cl, cb, c2);
    cluster_q<<<N / 256, 256, 0, stream>>>(z, cb, c2, out);
}

// Round 5
// 41.007 us; speedup vs baseline: 1.8577x; 1.0174x over previous
//
#include <hip/hip_runtime.h>

// Clustering layer: q[n,k] = t-dist kernel of ||z_n - c_k||^2, row-normalized.
// N=131072, K=100 (pad->112), D=256. f32 in/out; f16 MFMA for the dot products.
//
// R4: occupancy push. 512-thread blocks (8 waves), 32 rows/wave (acc[2][7]),
//     launch_bounds(512,4) -> 4 waves/SIMD (VGPR<=128), 2 blocks/CU (112KB LDS).
//     B panel in swizzled LDS (R3), depth-1 A-prefetch (R2). Theory: R3's 2
//     waves/SIMD phase-lock -> bursty vmem issue -> BW underutilized; 4 waves
//     decorrelate. Effective mem-sys floor ~31us (L3 ~= HBM-class BW).

typedef __attribute__((ext_vector_type(8))) _Float16 f16x8;
typedef __attribute__((ext_vector_type(4))) _Float16 f16x4;
typedef __attribute__((ext_vector_type(4))) float    f32x4;

#define DDIM 256
#define KCL  100
#define KPAD 112   // 7 * 16
#define NT   7     // column tiles of 16

// ---------------- kernel 1: clusters f32 -> f16 (padded) + ||c||^2 ----------
__global__ __launch_bounds__(64) void prep_clusters(const float* __restrict__ c,
                                                    _Float16* __restrict__ cb,
                                                    float* __restrict__ c2) {
    const int r    = blockIdx.x;    // 0..111
    const int lane = threadIdx.x;   // 0..63, each lane handles 4 elems
    f32x4 v = {0.f, 0.f, 0.f, 0.f};
    if (r < KCL) {
        v = reinterpret_cast<const f32x4*>(c)[r * (DDIM / 4) + lane];
    }
    f16x4 b;
    b[0] = (_Float16)v[0]; b[1] = (_Float16)v[1];
    b[2] = (_Float16)v[2]; b[3] = (_Float16)v[3];
    reinterpret_cast<f16x4*>(cb)[r * (DDIM / 4) + lane] = b;

    float ss = v[0]*v[0] + v[1]*v[1] + v[2]*v[2] + v[3]*v[3];
    #pragma unroll
    for (int m = 1; m < 64; m <<= 1) ss += __shfl_xor(ss, m);
    if (lane == 0) c2[r] = ss;
}

// ---------------- kernel 2: main fused GEMM + epilogue -----------------------
// Block = 512 threads = 8 waves. Each wave: 32 rows x 112 cols (2x7 MFMA tiles).
// Grid = N/256 blocks. B panel lives in swizzled LDS.
__global__ __launch_bounds__(512, 4) void cluster_q(const float* __restrict__ z,
                                                    const _Float16* __restrict__ cb,
                                                    const float* __restrict__ c2,
                                                    float* __restrict__ out) {
    __shared__ _Float16 Bs[KPAD * DDIM];   // 57,344 B

    const int tid  = threadIdx.x;
    const int lane = tid & 63;
    const int wv   = tid >> 6;             // 0..7
    const int g    = lane >> 4;            // k-group 0..3
    const int c16  = lane & 15;            // row (A) / col (B) within tile

    // ---- stage B panel into LDS, swizzled: byte ^= (row&7)<<4 ----
    // 112 rows x 512 B = 3584 chunks of 16 B; 512 threads x 7 iters.
    #pragma unroll
    for (int j = 0; j < 7; ++j) {
        const int idx  = j * 512 + tid;
        const int r    = idx >> 5;         // row 0..111
        const int cw   = idx & 31;         // 16B chunk within row
        f16x8 v = *reinterpret_cast<const f16x8*>(cb + r * DDIM + cw * 8);
        *reinterpret_cast<f16x8*>(reinterpret_cast<char*>(Bs)
            + r * 512 + ((cw * 16) ^ ((r & 7) << 4))) = v;
    }
    __syncthreads();

    const long rowbase = (long)blockIdx.x * 256 + wv * 32;

    f32x4 acc[2][NT];
    #pragma unroll
    for (int i = 0; i < 2; ++i)
        #pragma unroll
        for (int t = 0; t < NT; ++t)
            acc[i][t] = f32x4{0.f, 0.f, 0.f, 0.f};

    float zsq[2] = {0.f, 0.f};

    // per-lane A pointers: rows (i*16 + c16), k-offset 8*g
    const float* p0 = z + (rowbase + c16) * DDIM + 8 * g;
    const float* p1 = p0 + 16 * DDIM;

    // per-lane swizzled B row bases
    const int rx = (c16 & 7) << 4;
    const char* bbase = reinterpret_cast<const char*>(Bs) + c16 * 512;

    // prefetch step 0 A
    f32x4 lo0 = *reinterpret_cast<const f32x4*>(p0);
    f32x4 hi0 = *reinterpret_cast<const f32x4*>(p0 + 4);
    f32x4 lo1 = *reinterpret_cast<const f32x4*>(p1);
    f32x4 hi1 = *reinterpret_cast<const f32x4*>(p1 + 4);

    // K loop: 8 steps of 32. A from global (prefetched), B from swizzled LDS.
    // A and B use identical (group,reg)->k indexing -> HW k-slot convention
    // cancels; only the C/D layout (epilogue) is load-bearing.
    #pragma unroll 1
    for (int s = 0; s < 8; ++s) {
        const int kn = (s < 7) ? 32 * (s + 1) : 0;   // next-step prefetch
        f32x4 nlo0 = *reinterpret_cast<const f32x4*>(p0 + kn);
        f32x4 nhi0 = *reinterpret_cast<const f32x4*>(p0 + kn + 4);
        f32x4 nlo1 = *reinterpret_cast<const f32x4*>(p1 + kn);
        f32x4 nhi1 = *reinterpret_cast<const f32x4*>(p1 + kn + 4);

        zsq[0] += lo0[0]*lo0[0] + lo0[1]*lo0[1] + lo0[2]*lo0[2] + lo0[3]*lo0[3]
                + hi0[0]*hi0[0] + hi0[1]*hi0[1] + hi0[2]*hi0[2] + hi0[3]*hi0[3];
        zsq[1] += lo1[0]*lo1[0] + lo1[1]*lo1[1] + lo1[2]*lo1[2] + lo1[3]*lo1[3]
                + hi1[0]*hi1[0] + hi1[1]*hi1[1] + hi1[2]*hi1[2] + hi1[3]*hi1[3];

        f16x8 a0, a1;
        a0[0] = (_Float16)lo0[0]; a0[1] = (_Float16)lo0[1];
        a0[2] = (_Float16)lo0[2]; a0[3] = (_Float16)lo0[3];
        a0[4] = (_Float16)hi0[0]; a0[5] = (_Float16)hi0[1];
        a0[6] = (_Float16)hi0[2]; a0[7] = (_Float16)hi0[3];
        a1[0] = (_Float16)lo1[0]; a1[1] = (_Float16)lo1[1];
        a1[2] = (_Float16)lo1[2]; a1[3] = (_Float16)lo1[3];
        a1[4] = (_Float16)hi1[0]; a1[5] = (_Float16)hi1[1];
        a1[6] = (_Float16)hi1[2]; a1[7] = (_Float16)hi1[3];

        const int sb = (64 * s + 16 * g) ^ rx;
        #pragma unroll
        for (int t = 0; t < NT; ++t) {
            f16x8 b = *reinterpret_cast<const f16x8*>(bbase + t * 16 * 512 + sb);
            acc[0][t] = __builtin_amdgcn_mfma_f32_16x16x32_f16(a0, b, acc[0][t], 0, 0, 0);
            acc[1][t] = __builtin_amdgcn_mfma_f32_16x16x32_f16(a1, b, acc[1][t], 0, 0, 0);
        }

        lo0 = nlo0; hi0 = nhi0; lo1 = nlo1; hi1 = nhi1;
    }

    // ||z_row||^2: sum the 4 k-groups (lanes differing in bits 4..5)
    #pragma unroll
    for (int i = 0; i < 2; ++i) {
        zsq[i] += __shfl_xor(zsq[i], 16);
        zsq[i] += __shfl_xor(zsq[i], 32);
    }
    // now lane l holds z2 of row (l & 15) (plus i*16)

    float c2v[NT];
    #pragma unroll
    for (int t = 0; t < NT; ++t) c2v[t] = c2[t * 16 + c16];

    // Epilogue. C/D layout (verified, guide §3): col = lane&15, row = g*4 + reg.
    #pragma unroll
    for (int i = 0; i < 2; ++i) {
        #pragma unroll
        for (int j = 0; j < 4; ++j) {
            const int r = 4 * g + j;                 // row within 16-tile
            const float z2 = __shfl(zsq[i], r);      // lane r holds row r's norm
            float qv[NT];
            float rs = 0.f;
            #pragma unroll
            for (int t = 0; t < NT; ++t) {
                const float dot = acc[i][t][j];
                const float d2 = fmaxf(z2 + c2v[t] - 2.f * dot, 0.f);
                const float q = __builtin_amdgcn_rcpf(1.f + d2);
                qv[t] = q;
                if (t < 6 || c16 < 4) rs += q;       // mask padded cols 100..111
            }
            // row sum across the 16 lanes of this group (cols)
            rs += __shfl_xor(rs, 1);
            rs += __shfl_xor(rs, 2);
            rs += __shfl_xor(rs, 4);
            rs += __shfl_xor(rs, 8);
            const float rinv = __builtin_amdgcn_rcpf(rs);

            float* orow = out + (rowbase + i * 16 + r) * KCL;
            #pragma unroll
            for (int t = 0; t < NT; ++t) {
                const int col = t * 16 + c16;
                if (col < KCL)
                    orow[col] = qv[t] * rinv;
            }
        }
    }
}

// ---------------- launcher ---------------------------------------------------
extern "C" void kernel_launch(void* const* d_in, const int* in_sizes, int n_in,
                              void* d_out, int out_size, void* d_ws, size_t ws_size,
                              hipStream_t stream) {
    const float* z  = (const float*)d_in[0];
    const float* cl = (const float*)d_in[1];
    float* out = (float*)d_out;

    _Float16* cb = (_Float16*)d_ws;                                  // 112*256*2 B
    float*    c2 = (float*)((char*)d_ws + KPAD * DDIM * sizeof(_Float16));

    const int N = in_sizes[0] / DDIM;   // 131072

    prep_clusters<<<KPAD, 64, 0, stream>>>(cl, cb, c2);
    cluster_q<<<N / 256, 512, 0, stream>>>(z, cb, c2, out);
}

// Round 6
// 38.998 us; speedup vs baseline: 1.9534x; 1.0515x over previous
//
#include <hip/hip_runtime.h>

// Clustering layer: q[n,k] = t-dist kernel of ||z_n - c_k||^2, row-normalized.
// N=131072, K=100 (pad->112), D=256. f32 in/out; f16 MFMA for the dot products.
//
// R5: single fused kernel. Each block converts cl (f32, 100KB, L2-resident)
//     -> swizzled f16 LDS panel + inline ||c||^2 (32-lane shfl reduce -> LDS).
//     No prep kernel, no workspace dependency. Step-0 A prefetch issued
//     BEFORE staging (hides first HBM latency under staging loads).
//     R4 post-mortem: occupancy 2->4 waves/SIMD was neutral; pipes all slack;
//     suspects = fixed launch/serialization overhead vs mixed-BW ceiling.

typedef __attribute__((ext_vector_type(8))) _Float16 f16x8;
typedef __attribute__((ext_vector_type(4))) float    f32x4;

#define DDIM 256
#define KCL  100
#define KPAD 112   // 7 * 16
#define NT   7     // column tiles of 16

// Block = 512 threads = 8 waves. Each wave: 32 rows x 112 cols (2x7 MFMA tiles).
// Grid = N/256 blocks. B panel lives in swizzled LDS.
__global__ __launch_bounds__(512, 4) void cluster_q(const float* __restrict__ z,
                                                    const float* __restrict__ cl,
                                                    float* __restrict__ out) {
    __shared__ _Float16 Bs[KPAD * DDIM];   // 57,344 B
    __shared__ float    c2s[KPAD];         // +448 B

    const int tid  = threadIdx.x;
    const int lane = tid & 63;
    const int wv   = tid >> 6;             // 0..7
    const int g    = lane >> 4;            // k-group 0..3
    const int c16  = lane & 15;            // row (A) / col (B) within tile

    const long rowbase = (long)blockIdx.x * 256 + wv * 32;

    // per-lane A pointers: rows (i*16 + c16), k-offset 8*g
    const float* p0 = z + (rowbase + c16) * DDIM + 8 * g;
    const float* p1 = p0 + 16 * DDIM;

    // ---- issue step-0 A prefetch FIRST (latency hides under staging) ----
    f32x4 lo0 = *reinterpret_cast<const f32x4*>(p0);
    f32x4 hi0 = *reinterpret_cast<const f32x4*>(p0 + 4);
    f32x4 lo1 = *reinterpret_cast<const f32x4*>(p1);
    f32x4 hi1 = *reinterpret_cast<const f32x4*>(p1 + 4);

    // ---- stage B panel: read cl (f32) -> convert -> swizzled f16 LDS,
    //      and reduce ||c||^2 inline. 112 rows x 32 chunks of 32B(f32)/16B(f16);
    //      512 threads x 7 iters; each j-iter: 16 rows x 32 chunks,
    //      one row per 32 consecutive lanes. Swizzle: byte ^= (row&7)<<4.
    #pragma unroll
    for (int j = 0; j < 7; ++j) {
        const int idx = j * 512 + tid;
        const int r   = idx >> 5;          // row 0..111
        const int cw  = idx & 31;          // chunk within row
        f32x4 a = {0.f, 0.f, 0.f, 0.f}, b = {0.f, 0.f, 0.f, 0.f};
        if (r < KCL) {
            const f32x4* src = reinterpret_cast<const f32x4*>(cl) + r * 64 + cw * 2;
            a = src[0];
            b = src[1];
        }
        f16x8 v;
        v[0] = (_Float16)a[0]; v[1] = (_Float16)a[1];
        v[2] = (_Float16)a[2]; v[3] = (_Float16)a[3];
        v[4] = (_Float16)b[0]; v[5] = (_Float16)b[1];
        v[6] = (_Float16)b[2]; v[7] = (_Float16)b[3];
        *reinterpret_cast<f16x8*>(reinterpret_cast<char*>(Bs)
            + r * 512 + ((cw * 16) ^ ((r & 7) << 4))) = v;

        float ss = a[0]*a[0] + a[1]*a[1] + a[2]*a[2] + a[3]*a[3]
                 + b[0]*b[0] + b[1]*b[1] + b[2]*b[2] + b[3]*b[3];
        ss += __shfl_xor(ss, 1);
        ss += __shfl_xor(ss, 2);
        ss += __shfl_xor(ss, 4);
        ss += __shfl_xor(ss, 8);
        ss += __shfl_xor(ss, 16);          // row sum within each 32-lane half
        if ((lane & 31) == 0) c2s[r] = ss;
    }
    __syncthreads();

    f32x4 acc[2][NT];
    #pragma unroll
    for (int i = 0; i < 2; ++i)
        #pragma unroll
        for (int t = 0; t < NT; ++t)
            acc[i][t] = f32x4{0.f, 0.f, 0.f, 0.f};

    float zsq[2] = {0.f, 0.f};

    // per-lane swizzled B row bases
    const int rx = (c16 & 7) << 4;
    const char* bbase = reinterpret_cast<const char*>(Bs) + c16 * 512;

    // K loop: 8 steps of 32. A from global (depth-1 prefetch), B from LDS.
    // A and B use identical (group,reg)->k indexing -> HW k-slot convention
    // cancels; only the C/D layout (epilogue) is load-bearing.
    #pragma unroll 1
    for (int s = 0; s < 8; ++s) {
        const int kn = (s < 7) ? 32 * (s + 1) : 0;   // next-step prefetch
        f32x4 nlo0 = *reinterpret_cast<const f32x4*>(p0 + kn);
        f32x4 nhi0 = *reinterpret_cast<const f32x4*>(p0 + kn + 4);
        f32x4 nlo1 = *reinterpret_cast<const f32x4*>(p1 + kn);
        f32x4 nhi1 = *reinterpret_cast<const f32x4*>(p1 + kn + 4);

        zsq[0] += lo0[0]*lo0[0] + lo0[1]*lo0[1] + lo0[2]*lo0[2] + lo0[3]*lo0[3]
                + hi0[0]*hi0[0] + hi0[1]*hi0[1] + hi0[2]*hi0[2] + hi0[3]*hi0[3];
        zsq[1] += lo1[0]*lo1[0] + lo1[1]*lo1[1] + lo1[2]*lo1[2] + lo1[3]*lo1[3]
                + hi1[0]*hi1[0] + hi1[1]*hi1[1] + hi1[2]*hi1[2] + hi1[3]*hi1[3];

        f16x8 a0, a1;
        a0[0] = (_Float16)lo0[0]; a0[1] = (_Float16)lo0[1];
        a0[2] = (_Float16)lo0[2]; a0[3] = (_Float16)lo0[3];
        a0[4] = (_Float16)hi0[0]; a0[5] = (_Float16)hi0[1];
        a0[6] = (_Float16)hi0[2]; a0[7] = (_Float16)hi0[3];
        a1[0] = (_Float16)lo1[0]; a1[1] = (_Float16)lo1[1];
        a1[2] = (_Float16)lo1[2]; a1[3] = (_Float16)lo1[3];
        a1[4] = (_Float16)hi1[0]; a1[5] = (_Float16)hi1[1];
        a1[6] = (_Float16)hi1[2]; a1[7] = (_Float16)hi1[3];

        const int sb = (64 * s + 16 * g) ^ rx;
        #pragma unroll
        for (int t = 0; t < NT; ++t) {
            f16x8 b = *reinterpret_cast<const f16x8*>(bbase + t * 16 * 512 + sb);
            acc[0][t] = __builtin_amdgcn_mfma_f32_16x16x32_f16(a0, b, acc[0][t], 0, 0, 0);
            acc[1][t] = __builtin_amdgcn_mfma_f32_16x16x32_f16(a1, b, acc[1][t], 0, 0, 0);
        }

        lo0 = nlo0; hi0 = nhi0; lo1 = nlo1; hi1 = nhi1;
    }

    // ||z_row||^2: sum the 4 k-groups (lanes differing in bits 4..5)
    #pragma unroll
    for (int i = 0; i < 2; ++i) {
        zsq[i] += __shfl_xor(zsq[i], 16);
        zsq[i] += __shfl_xor(zsq[i], 32);
    }
    // now lane l holds z2 of row (l & 15) (plus i*16)

    float c2v[NT];
    #pragma unroll
    for (int t = 0; t < NT; ++t) c2v[t] = c2s[t * 16 + c16];

    // Epilogue. C/D layout (verified, guide §3): col = lane&15, row = g*4 + reg.
    #pragma unroll
    for (int i = 0; i < 2; ++i) {
        #pragma unroll
        for (int j = 0; j < 4; ++j) {
            const int r = 4 * g + j;                 // row within 16-tile
            const float z2 = __shfl(zsq[i], r);      // lane r holds row r's norm
            float qv[NT];
            float rs = 0.f;
            #pragma unroll
            for (int t = 0; t < NT; ++t) {
                const float dot = acc[i][t][j];
                const float d2 = fmaxf(z2 + c2v[t] - 2.f * dot, 0.f);
                const float q = __builtin_amdgcn_rcpf(1.f + d2);
                qv[t] = q;
                if (t < 6 || c16 < 4) rs += q;       // mask padded cols 100..111
            }
            // row sum across the 16 lanes of this group (cols)
            rs += __shfl_xor(rs, 1);
            rs += __shfl_xor(rs, 2);
            rs += __shfl_xor(rs, 4);
            rs += __shfl_xor(rs, 8);
            const float rinv = __builtin_amdgcn_rcpf(rs);

            float* orow = out + (rowbase + i * 16 + r) * KCL;
            #pragma unroll
            for (int t = 0; t < NT; ++t) {
                const int col = t * 16 + c16;
                if (col < KCL)
                    orow[col] = qv[t] * rinv;
            }
        }
    }
}

// ---------------- launcher ---------------------------------------------------
extern "C" void kernel_launch(void* const* d_in, const int* in_sizes, int n_in,
                              void* d_out, int out_size, void* d_ws, size_t ws_size,
                              hipStream_t stream) {
    const float* z  = (const float*)d_in[0];
    const float* cl = (const float*)d_in[1];
    float* out = (float*)d_out;

    const int N = in_sizes[0] / DDIM;   // 131072

    cluster_q<<<N / 256, 512, 0, stream>>>(z, cl, out);
}